// Round 6
// baseline (159.359 us; speedup 1.0000x reference)
//
#include <hip/hip_runtime.h>

#define HH 128
#define WW 128
#define BB 64
#define OO 32
#define LP 132   // f32 pitch: rows 16B-aligned (float4 staging), mild bank rotation

typedef float f32x2 __attribute__((ext_vector_type(2)));  // native vector: ok for
                                                          // __builtin_nontemporal_store

// Experiment ledger (dur_us = ~82us harness fill + kernel):
//   R0 pitch128 1px/thr scalar stores ......... 152.9
//   R2 pitch132 (bank fix) .................... 150.0
//   R3 512thr/128VGPR/rolled (ILP axis) ....... 149.5  <- occupancy/VGPR excluded
//   R4 row-pair f2, 1 ds_read2_b64/px ......... 150.0  <- DS issue-count excluded
//   R5 compile fail (nontemporal needs native vec type) -> this is R5 retried
// Main loop issues ~25us/CU of work but kernel measures ~68us; effective write
// BW ~2.3 TB/s vs the harness fill's 6.5 TB/s on identical HBM. ROUND-5 AXIS:
// the store path. 2 px/thread in x -> one dwordx2 per thread = 512B per wave
// store instr (was 256B), and nontemporal (nt) stores so the 134MB output
// stream doesn't allocate/evict through the 32MB L2.
// LDS gather cost is held ~constant: f32 layout, lane x-stride 2 -> 4-way
// bank aliasing on 4x ds_read2_b32, same DS-cycle budget as R4 (R2<->R4
// measured neutral, so this perturbation is bounded ~+-3us).
// Coordinate clamp into [0, 126.99999] replaces the reference's index clamp
// (equivalent within ~1e-5 tap weight; keeps +1/+LP taps in-bounds).
__launch_bounds__(1024, 4)
__global__ void sample_kernel(const float* __restrict__ X,
                              const float* __restrict__ eps,
                              const float* __restrict__ tmin,
                              const float* __restrict__ tmax,
                              float* __restrict__ out) {
    __shared__ float img[HH * LP];   // 67584 B
    __shared__ float scoef[4][6];

    const int bid = blockIdx.x;
    const int og  = bid & 7;          // consecutive blocks share b -> L2 reuse on X
    const int b   = bid >> 3;
    const int tid = threadIdx.x;

    if (tid < 4) {
        const int o = og * 4 + tid;
        float th[7];
#pragma unroll
        for (int i = 0; i < 7; ++i) {
            const float mn = tmin[i], mx = tmax[i];
            th[i] = mn + (mx - mn) * eps[o * 7 + i];
        }
        const float ang = th[0], sx = th[1], sy = th[2], px = th[3],
                    py = th[4], tx = th[5], ty = th[6];
        const float c = cosf(ang), s = sinf(ang);
        const float half = 0.5f * (WW - 1);  // 63.5
        scoef[tid][0] = (c * sx - s * py) * half;   // cx0
        scoef[tid][1] = (c * px - s * sy) * half;   // cx1
        scoef[tid][2] = (tx + 1.0f) * half;         // cxt
        scoef[tid][3] = (s * sx + c * py) * half;   // cy0
        scoef[tid][4] = (s * px + c * sy) * half;   // cy1
        scoef[tid][5] = (ty + 1.0f) * half;         // cyt
    }

    // Stage image b -> LDS: coalesced float4 loads AND float4 LDS writes
    // (pitch 132 floats = 33 float4; dest float4 index = g + g/32).
    {
        const float4* __restrict__ src = (const float4*)(X + b * (HH * WW));
        float4* __restrict__ dst = (float4*)img;
#pragma unroll
        for (int i = 0; i < 4; ++i) {
            const int g = tid + i * 1024;      // float4 index, 0..4095
            dst[g + (g >> 5)] = src[g];        // ds_write_b128, 16B-aligned
        }
    }
    __syncthreads();

    const int x2 = (tid & 63) << 1;          // 0,2,..,126; one wave = one full row
    const int h0 = tid >> 6;                 // 0..15
    const float step  = 2.0f / 127.0f;
    const float rstep = 16.0f * step;        // i-loop row stride
    const float Xg0 = -1.0f + x2 * step;
    const float Yg0 = -1.0f + h0 * step;
    const float hi  = 126.999992f;           // nextbelow(127)

#pragma unroll
    for (int j = 0; j < 4; ++j) {
        const int o = og * 4 + j;
        const float cx0 = scoef[j][0];
        const float cx1 = scoef[j][1];
        const float cxt = scoef[j][2];
        const float cy0 = scoef[j][3];
        const float cy1 = scoef[j][4];
        const float cyt = scoef[j][5];

        const float ax = cx0 * step;         // per-column sample-coord deltas
        const float ay = cy0 * step;
        const float dxr = cx1 * rstep;       // per-i (16 rows) deltas
        const float dyr = cy1 * rstep;

        float x = fmaf(cx1, Yg0, fmaf(cx0, Xg0, cxt));
        float y = fmaf(cy1, Yg0, fmaf(cy0, Xg0, cyt));

        f32x2* __restrict__ outp = (f32x2*)(
            out + ((size_t)(o * BB + b) << 14) + h0 * WW + x2);

#pragma unroll 4
        for (int i = 0; i < 8; ++i) {
            // pixel A at (x2, row), pixel B at (x2+1, row)
            float r[2];
            const float xb = x + ax;
            const float yb = y + ay;
#pragma unroll
            for (int k = 0; k < 2; ++k) {
                const float xs = k ? xb : x;
                const float ys = k ? yb : y;
                const float xc = __builtin_amdgcn_fmed3f(xs, 0.0f, hi);
                const float yc = __builtin_amdgcn_fmed3f(ys, 0.0f, hi);
                const float x0f = floorf(xc);
                const float y0f = floorf(yc);
                const float wx = xc - x0f;
                const float wy = yc - y0f;
                const int idx = (int)fmaf(y0f, (float)LP, x0f);  // exact (< 2^24)

                const float Ia = img[idx];
                const float Ic = img[idx + 1];        // ds_read2_b32 (off 0,1)
                const float Ib = img[idx + LP];
                const float Id = img[idx + LP + 1];   // ds_read2_b32 (off 132,133)

                const float top = fmaf(wx, Ic - Ia, Ia);
                const float bot = fmaf(wx, Id - Ib, Ib);
                r[k] = fmaf(wy, bot - top, top);
            }
            f32x2 v; v.x = r[0]; v.y = r[1];
            __builtin_nontemporal_store(v, outp);

            outp += 16 * WW / 2;   // 16 rows ahead
            x += dxr;
            y += dyr;
        }
    }
}

extern "C" void kernel_launch(void* const* d_in, const int* in_sizes, int n_in,
                              void* d_out, int out_size, void* d_ws, size_t ws_size,
                              hipStream_t stream) {
    const float* X    = (const float*)d_in[0];
    const float* eps  = (const float*)d_in[1];
    const float* tmin = (const float*)d_in[2];
    const float* tmax = (const float*)d_in[3];
    float* out = (float*)d_out;

    const int nblocks = BB * 8;  // 512
    sample_kernel<<<nblocks, 1024, 0, stream>>>(X, eps, tmin, tmax, out);
}

// Round 8
// 153.416 us; speedup vs baseline: 1.0387x; 1.0387x over previous
//
#include <hip/hip_runtime.h>

#define HH 128
#define WW 128
#define BB 64
#define OO 32
#define LP 132   // f32 pitch: rows 16B-aligned (float4 staging), mild bank rotation

// Experiment ledger (dur_us):
//   R0 pitch128, strided-row waves, scalar st ... 152.9
//   R1 pitch129 (broke f4 staging, spills) ...... 169.6
//   R2 pitch132 ................................. 150.0
//   R3 512thr/128VGPR/rolled (ILP axis) ......... 149.5   occupancy/VGPR excluded
//   R4 row-pair f2, 1 ds_read2_b64/px ........... 150.0   DS issue-count excluded
//   R6 2px/thr dwordx2 + nt (confounded) ........ 159.4
//   R7 infra failure (container) ................ this is R7 retried, unchanged
// Pattern: removing modeled cost never helps (R3,R4); adding cost always hurts
// (R1,R6) -> kernel is likely AT a floor. Best-fit model: timed region =
// fill(82) + fixed harness copy(~43) + kernel(~25, of which ~21 is its own
// 134MB HBM-write roofline). ROUND-7 = last World-A discriminator: change ONLY
// the store stream. Waves previously wrote 256B chunks at 4KB stride into
// scattered windows; now each 2-wave group owns a contiguous 16-row band and
// walks it row-by-row -> near-sequential ascending write stream per wave, plus
// nontemporal flag (no L2 allocation for the 134MB stream). Gather/VALU/DS
// identical to R2. If neutral, kernel has met its structural constraint.
// Coordinate clamp into [0, 126.99999] replaces the reference's index clamp
// (equivalent within ~1e-5 tap weight; keeps +1/+LP taps in-bounds) so each
// bilinear row-pair compiles to one ds_read2_b32 (offsets 0,1 / 132,133).
__launch_bounds__(1024, 8)
__global__ void sample_kernel(const float* __restrict__ X,
                              const float* __restrict__ eps,
                              const float* __restrict__ tmin,
                              const float* __restrict__ tmax,
                              float* __restrict__ out) {
    __shared__ float img[HH * LP];   // 67584 B -> 2 blocks/CU
    __shared__ float scoef[4][6];

    const int bid = blockIdx.x;
    const int og  = bid & 7;          // consecutive blocks share b -> L2 reuse on X
    const int b   = bid >> 3;
    const int tid = threadIdx.x;

    if (tid < 4) {
        const int o = og * 4 + tid;
        float th[7];
#pragma unroll
        for (int i = 0; i < 7; ++i) {
            const float mn = tmin[i], mx = tmax[i];
            th[i] = mn + (mx - mn) * eps[o * 7 + i];
        }
        const float ang = th[0], sx = th[1], sy = th[2], px = th[3],
                    py = th[4], tx = th[5], ty = th[6];
        const float c = cosf(ang), s = sinf(ang);
        const float half = 0.5f * (WW - 1);  // 63.5
        scoef[tid][0] = (c * sx - s * py) * half;   // cx0
        scoef[tid][1] = (c * px - s * sy) * half;   // cx1
        scoef[tid][2] = (tx + 1.0f) * half;         // cxt
        scoef[tid][3] = (s * sx + c * py) * half;   // cy0
        scoef[tid][4] = (s * px + c * sy) * half;   // cy1
        scoef[tid][5] = (ty + 1.0f) * half;         // cyt
    }

    // Stage image b -> LDS: coalesced float4 loads AND float4 LDS writes
    // (pitch 132 floats = 33 float4; dest float4 index = g + g/32).
    {
        const float4* __restrict__ src = (const float4*)(X + b * (HH * WW));
        float4* __restrict__ dst = (float4*)img;
#pragma unroll
        for (int i = 0; i < 4; ++i) {
            const int g = tid + i * 1024;      // float4 index, 0..4095
            dst[g + (g >> 5)] = src[g];        // ds_write_b128, 16B-aligned
        }
    }
    __syncthreads();

    const int w    = tid & (WW - 1);
    const int band = tid >> 7;               // 0..7: contiguous 16-row band
    const float step = 2.0f / 127.0f;
    const float Xg  = -1.0f + w * step;
    const float Yg0 = -1.0f + (band * 16) * step;
    const float hi  = 126.999992f;           // nextbelow(127)

#pragma unroll
    for (int j = 0; j < 4; ++j) {
        const int o = og * 4 + j;
        const float cx0 = scoef[j][0];
        const float cx1 = scoef[j][1];
        const float cxt = scoef[j][2];
        const float cy0 = scoef[j][3];
        const float cy1 = scoef[j][4];
        const float cyt = scoef[j][5];

        float x = fmaf(cx1, Yg0, fmaf(cx0, Xg, cxt));
        float y = fmaf(cy1, Yg0, fmaf(cy0, Xg, cyt));
        const float dx = cx1 * step;         // one ROW per i-iteration now
        const float dy = cy1 * step;

        float* __restrict__ outp =
            out + ((size_t)(o * BB + b) * (HH * WW)) + band * 16 * WW + w;

#pragma unroll
        for (int i = 0; i < 16; ++i) {
            const float xc = __builtin_amdgcn_fmed3f(x, 0.0f, hi);
            const float yc = __builtin_amdgcn_fmed3f(y, 0.0f, hi);
            const float x0f = floorf(xc);
            const float y0f = floorf(yc);
            const float wx = xc - x0f;
            const float wy = yc - y0f;
            const int idx = (int)fmaf(y0f, (float)LP, x0f);  // exact (< 2^24)

            const float Ia = img[idx];
            const float Ic = img[idx + 1];        // ds_read2_b32 (off 0,1)
            const float Ib = img[idx + LP];
            const float Id = img[idx + LP + 1];   // ds_read2_b32 (off 132,133)

            const float top = fmaf(wx, Ic - Ia, Ia);
            const float bot = fmaf(wx, Id - Ib, Ib);
            __builtin_nontemporal_store(fmaf(wy, bot - top, top), outp);

            outp += WW;            // next row: sequential write stream per wave
            x += dx;
            y += dy;
        }
    }
}

extern "C" void kernel_launch(void* const* d_in, const int* in_sizes, int n_in,
                              void* d_out, int out_size, void* d_ws, size_t ws_size,
                              hipStream_t stream) {
    const float* X    = (const float*)d_in[0];
    const float* eps  = (const float*)d_in[1];
    const float* tmin = (const float*)d_in[2];
    const float* tmax = (const float*)d_in[3];
    float* out = (float*)d_out;

    const int nblocks = BB * 8;  // 512: 2 per CU, LDS-capped full occupancy
    sample_kernel<<<nblocks, 1024, 0, stream>>>(X, eps, tmin, tmax, out);
}